// Round 1
// baseline (127.768 us; speedup 1.0000x reference)
//
#include <hip/hip_runtime.h>
#include <hip/hip_bf16.h>
#include <stdint.h>

#define B_ 4
#define S_ 4096
#define D_ 1024
#define TOPK_ 2048

#define BM 128
#define BN 128
#define BK 64
#define NT (D_ / BK)  // 16

typedef __attribute__((ext_vector_type(8))) short bf16x8;
typedef __attribute__((ext_vector_type(4))) float f32x4;

// RNE fp32 -> bf16 pack (two floats -> one u32, low|high)
__device__ __forceinline__ unsigned pack2bf16(float a, float b) {
  unsigned ua = __float_as_uint(a);
  unsigned ub = __float_as_uint(b);
  ua += 0x7fffu + ((ua >> 16) & 1u);
  ub += 0x7fffu + ((ub >> 16) & 1u);
  return (ua >> 16) | (ub & 0xffff0000u);
}

// ---------------- K1: router logits + out = x copy ----------------
// one wave per token; block = 4 waves; grid = B*S/4
__global__ __launch_bounds__(256) void k_router_copy(
    const float* __restrict__ x, const float* __restrict__ wr,
    float* __restrict__ out, float* __restrict__ logits) {
  const int lane = threadIdx.x & 63;
  const int token = blockIdx.x * 4 + (threadIdx.x >> 6);
  const float4* xr = (const float4*)(x + (size_t)token * D_);
  float4* orow = (float4*)(out + (size_t)token * D_);
  const float4* wrow = (const float4*)wr;
  double acc = 0.0;
#pragma unroll
  for (int i = 0; i < 4; ++i) {
    float4 v = xr[i * 64 + lane];
    float4 w = wrow[i * 64 + lane];
    orow[i * 64 + lane] = v;
    acc += (double)v.x * (double)w.x + (double)v.y * (double)w.y +
           (double)v.z * (double)w.z + (double)v.w * (double)w.w;
  }
#pragma unroll
  for (int off = 32; off; off >>= 1) acc += __shfl_down(acc, off);
  if (lane == 0) logits[token] = (float)acc;
}

// ---------------- K2: exact top-k via in-LDS bitonic sort ----------------
// composite key = (monotonic(float) << 32) | (S-1-s): distinct keys,
// ties in logit broken toward smaller s (matches stable lax.top_k).
__global__ __launch_bounds__(1024) void k_topk(
    const float* __restrict__ logits, unsigned* __restrict__ sel) {
  __shared__ uint64_t keys[S_];
  const int b = blockIdx.x;
  const float* lg = logits + b * S_;
  for (int s = threadIdx.x; s < S_; s += 1024) {
    unsigned u = __float_as_uint(lg[s]);
    u = (u & 0x80000000u) ? ~u : (u | 0x80000000u);  // order-preserving map
    keys[s] = ((uint64_t)u << 32) | (unsigned)(S_ - 1 - s);
  }
  __syncthreads();
  for (unsigned k = 2; k <= (unsigned)S_; k <<= 1) {
    for (unsigned j = k >> 1; j > 0; j >>= 1) {
      for (unsigned t = threadIdx.x; t < (unsigned)S_; t += 1024) {
        unsigned ixj = t ^ j;
        if (ixj > t) {
          bool up = ((t & k) == 0);
          uint64_t a = keys[t], c = keys[ixj];
          if ((a > c) == up) { keys[t] = c; keys[ixj] = a; }
        }
      }
      __syncthreads();
    }
  }
  // ascending sort: top-K live in [S-K, S)
  for (int t = threadIdx.x; t < TOPK_; t += 1024) {
    sel[b * TOPK_ + t] = (unsigned)(S_ - 1) - (unsigned)(keys[S_ - TOPK_ + t] & 0xffffffffu);
  }
}

// ---------------- K3: gathered bf16 GEMM + scatter ----------------
// C[m,e] = sum_d x[b, sel[m], d] * W[e, d]   (NT layout, both contract on d)
// 128x128 tile, BK=64, 8 waves (4M x 2N), reg-staged fp32->bf16 with
// XOR-swizzled LDS, 2-phase prefetch.
__global__ __launch_bounds__(512) void k_gemm_scatter(
    const float* __restrict__ x, const float* __restrict__ w,
    const unsigned* __restrict__ sel, float* __restrict__ out) {
  __shared__ __align__(16) unsigned short Alds[BM * BK];
  __shared__ __align__(16) unsigned short Blds[BN * BK];

  const int bid = blockIdx.x;
  const int b = bid >> 7;      // 128 blocks per batch
  const int rem = bid & 127;
  const int mb = rem >> 3;     // 0..15
  const int nb = rem & 7;      // 0..7

  const unsigned* selb = sel + b * TOPK_;
  const float* xb = x + (size_t)b * S_ * D_;
  float* outb = out + (size_t)b * S_ * D_;

  const int tid = threadIdx.x;
  const int lane = tid & 63;
  const int wid = tid >> 6;
  const int wm = wid >> 1;  // 0..3 (M)
  const int wn = wid & 1;   // 0..1 (N)

  // staging assignment: flat = r*512 + tid; row = flat>>4 (0..127), c4 = flat&15
  const float* asrc[4];
  const float* bsrc[4];
  int srow_[4], sc4_[4];
#pragma unroll
  for (int r = 0; r < 4; ++r) {
    int flat = r * 512 + tid;
    int row = flat >> 4;
    int c4 = flat & 15;
    srow_[r] = row;
    sc4_[r] = c4;
    asrc[r] = xb + (size_t)selb[mb * BM + row] * D_ + c4 * 4;  // gathered row
    bsrc[r] = w + (size_t)(nb * BN + row) * D_ + c4 * 4;
  }

  f32x4 acc[2][4];
#pragma unroll
  for (int i = 0; i < 2; ++i)
#pragma unroll
    for (int j = 0; j < 4; ++j) acc[i][j] = (f32x4)0.0f;

  float4 pa[4], pb[4];
#pragma unroll
  for (int r = 0; r < 4; ++r) {
    pa[r] = *(const float4*)(asrc[r]);
    pb[r] = *(const float4*)(bsrc[r]);
  }

  for (int t = 0; t < NT; ++t) {
    // store staged regs -> LDS (fp32->bf16, swizzled)
#pragma unroll
    for (int r = 0; r < 4; ++r) {
      int row = srow_[r], c4 = sc4_[r];
      int byte = row * 128 + c4 * 8;
      byte ^= (row & 7) << 4;
      uint2 va = make_uint2(pack2bf16(pa[r].x, pa[r].y), pack2bf16(pa[r].z, pa[r].w));
      uint2 vb = make_uint2(pack2bf16(pb[r].x, pb[r].y), pack2bf16(pb[r].z, pb[r].w));
      *(uint2*)((char*)Alds + byte) = va;
      *(uint2*)((char*)Blds + byte) = vb;
    }
    __syncthreads();

    // prefetch next K-tile while computing this one
    if (t + 1 < NT) {
      const int koff = (t + 1) * BK;
#pragma unroll
      for (int r = 0; r < 4; ++r) {
        pa[r] = *(const float4*)(asrc[r] + koff);
        pb[r] = *(const float4*)(bsrc[r] + koff);
      }
    }

#pragma unroll
    for (int kk = 0; kk < 2; ++kk) {
      bf16x8 af[2], bfr[4];
#pragma unroll
      for (int mi = 0; mi < 2; ++mi) {
        int rrow = wm * 32 + mi * 16 + (lane & 15);
        int byte = rrow * 128 + (kk * 32 + (lane >> 4) * 8) * 2;
        byte ^= (rrow & 7) << 4;
        af[mi] = *(const bf16x8*)((const char*)Alds + byte);
      }
#pragma unroll
      for (int nj = 0; nj < 4; ++nj) {
        int rrow = wn * 64 + nj * 16 + (lane & 15);
        int byte = rrow * 128 + (kk * 32 + (lane >> 4) * 8) * 2;
        byte ^= (rrow & 7) << 4;
        bfr[nj] = *(const bf16x8*)((const char*)Blds + byte);
      }
#pragma unroll
      for (int mi = 0; mi < 2; ++mi)
#pragma unroll
        for (int nj = 0; nj < 4; ++nj)
          acc[mi][nj] = __builtin_amdgcn_mfma_f32_16x16x32_bf16(af[mi], bfr[nj], acc[mi][nj], 0, 0, 0);
    }
    __syncthreads();
  }

  // epilogue: scatter transformed rows
#pragma unroll
  for (int mi = 0; mi < 2; ++mi) {
#pragma unroll
    for (int j = 0; j < 4; ++j) {
      int m = mb * BM + wm * 32 + mi * 16 + (lane >> 4) * 4 + j;
      unsigned srow = selb[m];
      float* orow = outb + (size_t)srow * D_;
#pragma unroll
      for (int nj = 0; nj < 4; ++nj) {
        int col = nb * BN + wn * 64 + nj * 16 + (lane & 15);
        orow[col] = acc[mi][nj][j];
      }
    }
  }
}

extern "C" void kernel_launch(void* const* d_in, const int* in_sizes, int n_in,
                              void* d_out, int out_size, void* d_ws, size_t ws_size,
                              hipStream_t stream) {
  (void)in_sizes; (void)n_in; (void)out_size; (void)ws_size;
  const float* x = (const float*)d_in[0];
  const float* wb = (const float*)d_in[1];
  const float* wr = (const float*)d_in[2];
  float* out = (float*)d_out;

  float* logits = (float*)d_ws;                                        // B*S floats = 64 KB
  unsigned* sel = (unsigned*)((char*)d_ws + (size_t)B_ * S_ * sizeof(float));  // B*K u32 = 32 KB

  k_router_copy<<<B_ * S_ / 4, 256, 0, stream>>>(x, wr, out, logits);
  k_topk<<<B_, 1024, 0, stream>>>(logits, sel);
  k_gemm_scatter<<<B_ * (TOPK_ / BM) * (D_ / BN), 512, 0, stream>>>(x, wb, sel, out);
}

// Round 2
// 79.270 us; speedup vs baseline: 1.6118x; 1.6118x over previous
//
#include <hip/hip_runtime.h>
#include <hip/hip_bf16.h>
#include <stdint.h>

#define B_ 4
#define S_ 4096
#define D_ 1024
#define TOPK_ 2048
#define NSEL_ (S_ - TOPK_)

#define BM 128
#define BN 128
#define BK 64
#define NT (D_ / BK)  // 16

typedef __attribute__((ext_vector_type(8))) short bf16x8;
typedef __attribute__((ext_vector_type(4))) float f32x4;

// RNE fp32 -> bf16 pack (two floats -> one u32, low|high)
__device__ __forceinline__ unsigned pack2bf16(float a, float b) {
  unsigned ua = __float_as_uint(a);
  unsigned ub = __float_as_uint(b);
  ua += 0x7fffu + ((ua >> 16) & 1u);
  ub += 0x7fffu + ((ub >> 16) & 1u);
  return (ua >> 16) | (ub & 0xffff0000u);
}

// order-preserving float -> u32 map
__device__ __forceinline__ unsigned mono_u32(float f) {
  unsigned u = __float_as_uint(f);
  return (u & 0x80000000u) ? ~u : (u | 0x80000000u);
}

// ---------------- K1: router logits ----------------
// one wave per token; block = 4 waves; grid = B*S/4
__global__ __launch_bounds__(256) void k_router(
    const float* __restrict__ x, const float* __restrict__ wr,
    float* __restrict__ logits) {
  const int lane = threadIdx.x & 63;
  const int token = blockIdx.x * 4 + (threadIdx.x >> 6);
  const float4* xr = (const float4*)(x + (size_t)token * D_);
  const float4* wrow = (const float4*)wr;
  double acc = 0.0;
#pragma unroll
  for (int i = 0; i < 4; ++i) {
    float4 v = xr[i * 64 + lane];
    float4 w = wrow[i * 64 + lane];
    acc += (double)v.x * (double)w.x + (double)v.y * (double)w.y +
           (double)v.z * (double)w.z + (double)v.w * (double)w.w;
  }
#pragma unroll
  for (int off = 32; off; off >>= 1) acc += __shfl_down(acc, off);
  if (lane == 0) logits[token] = (float)acc;
}

// ---------------- K2: exact top-k via 4-pass radix select ----------------
// Output: sel[b][K] (selected indices, order irrelevant for correctness) and
// notsel[b][S-K] (complement). Ties at threshold value broken toward smaller
// index (matches stable lax.top_k membership).
__global__ __launch_bounds__(1024) void k_select(
    const float* __restrict__ logits, unsigned* __restrict__ sel,
    unsigned* __restrict__ notsel) {
  __shared__ unsigned hist[256];
  __shared__ unsigned bc_digit, bc_need;
  __shared__ unsigned scanbuf[17];

  const int b = blockIdx.x;
  const int tid = threadIdx.x;
  const int lane = tid & 63;
  const int wave = tid >> 6;

  // 4 contiguous logits per thread (index-ordered assignment for tie ranks)
  float4 v = *(const float4*)(logits + b * S_ + tid * 4);
  unsigned k0 = mono_u32(v.x), k1 = mono_u32(v.y),
           k2 = mono_u32(v.z), k3 = mono_u32(v.w);

  unsigned prefix = 0, need = TOPK_;
#pragma unroll
  for (int pass = 0; pass < 4; ++pass) {
    const int shift = 24 - pass * 8;
    const unsigned maskhi = pass ? (0xFFFFFFFFu << (shift + 8)) : 0u;
    if (tid < 256) hist[tid] = 0;
    __syncthreads();  // B1 (also fences bc_* reads from prev pass)
    if ((k0 & maskhi) == prefix) atomicAdd(&hist[(k0 >> shift) & 255], 1u);
    if ((k1 & maskhi) == prefix) atomicAdd(&hist[(k1 >> shift) & 255], 1u);
    if ((k2 & maskhi) == prefix) atomicAdd(&hist[(k2 >> shift) & 255], 1u);
    if ((k3 & maskhi) == prefix) atomicAdd(&hist[(k3 >> shift) & 255], 1u);
    __syncthreads();  // B2
    if (wave == 0) {
      // lane owns bins [4*lane, 4*lane+3]
      uint4 h = *(const uint4*)(hist + lane * 4);
      unsigned t = h.x + h.y + h.z + h.w;
      unsigned inc = t;
#pragma unroll
      for (int off = 1; off < 64; off <<= 1) {
        unsigned u = __shfl_up(inc, off);
        if (lane >= off) inc += u;
      }
      unsigned total = __shfl(inc, 63);
      unsigned above = total - inc;  // sum over lanes > lane
      unsigned a3 = above;
      unsigned a2 = a3 + h.w;
      unsigned a1 = a2 + h.z;
      unsigned a0 = a1 + h.y;
      if (a3 < need && need <= a3 + h.w) { bc_digit = lane * 4 + 3; bc_need = need - a3; }
      else if (a2 < need && need <= a2 + h.z) { bc_digit = lane * 4 + 2; bc_need = need - a2; }
      else if (a1 < need && need <= a1 + h.y) { bc_digit = lane * 4 + 1; bc_need = need - a1; }
      else if (a0 < need && need <= a0 + h.x) { bc_digit = lane * 4 + 0; bc_need = need - a0; }
    }
    __syncthreads();  // B3
    prefix |= bc_digit << shift;
    need = bc_need;
  }

  const unsigned V = prefix;       // K-th largest key value
  const unsigned fneed = need;     // # of ==V elements to take (smallest idx)

  // packed (gt<<16)|eq counts, walked in index order within thread
  unsigned packed = 0;
  unsigned pk_excl0, pk_excl1, pk_excl2, pk_excl3;
  pk_excl0 = packed; if (k0 > V) packed += 1u << 16; else if (k0 == V) packed += 1u;
  pk_excl1 = packed; if (k1 > V) packed += 1u << 16; else if (k1 == V) packed += 1u;
  pk_excl2 = packed; if (k2 > V) packed += 1u << 16; else if (k2 == V) packed += 1u;
  pk_excl3 = packed; if (k3 > V) packed += 1u << 16; else if (k3 == V) packed += 1u;

  unsigned inc = packed;
#pragma unroll
  for (int off = 1; off < 64; off <<= 1) {
    unsigned u = __shfl_up(inc, off);
    if (lane >= off) inc += u;
  }
  if (lane == 63) scanbuf[wave] = inc;
  __syncthreads();
  if (tid < 16) {
    unsigned t = scanbuf[tid];
    unsigned winc = t;
#pragma unroll
    for (int off = 1; off < 16; off <<= 1) {
      unsigned u = __shfl_up(winc, off);
      if (tid >= off) winc += u;
    }
    scanbuf[tid] = winc - t;              // exclusive wave offset
    if (tid == 15) scanbuf[16] = winc;    // grand total
  }
  __syncthreads();
  const unsigned base = scanbuf[wave] + (inc - packed);
  const unsigned G_total = scanbuf[16] >> 16;  // count of > V

  unsigned* selb = sel + b * TOPK_;
  unsigned* notb = notsel + b * NSEL_;
#pragma unroll
  for (int i = 0; i < 4; ++i) {
    unsigned ki = (i == 0) ? k0 : (i == 1) ? k1 : (i == 2) ? k2 : k3;
    unsigned pe = (i == 0) ? pk_excl0 : (i == 1) ? pk_excl1 : (i == 2) ? pk_excl2 : pk_excl3;
    unsigned s = tid * 4 + i;
    unsigned gtE = (base + pe) >> 16;
    unsigned eqE = (base + pe) & 0xFFFFu;
    if (ki > V) {
      selb[gtE] = s;
    } else if (ki == V && eqE < fneed) {
      selb[G_total + eqE] = s;
    } else {
      unsigned eqTaken = (eqE < fneed) ? eqE : fneed;
      notb[s - gtE - eqTaken] = s;
    }
  }
}

// ---------------- K3: copy non-selected rows ----------------
// one block per row; 256 threads x float4 = 1024 floats
__global__ __launch_bounds__(256) void k_copy_rows(
    const float* __restrict__ x, const unsigned* __restrict__ notsel,
    float* __restrict__ out) {
  const int r = blockIdx.x;
  const int b = r >> 11;  // NSEL_ = 2048 rows per batch
  const unsigned s = notsel[r];
  const size_t off = ((size_t)b * S_ + s) * D_;
  const float4* src = (const float4*)(x + off);
  float4* dst = (float4*)(out + off);
  dst[threadIdx.x] = src[threadIdx.x];
}

// ---------------- K4: gathered bf16 GEMM + scatter ----------------
// C[m,e] = sum_d x[b, sel[m], d] * W[e, d]   (NT layout)
__global__ __launch_bounds__(512) void k_gemm_scatter(
    const float* __restrict__ x, const float* __restrict__ w,
    const unsigned* __restrict__ sel, float* __restrict__ out) {
  __shared__ __align__(16) unsigned short Alds[BM * BK];
  __shared__ __align__(16) unsigned short Blds[BN * BK];

  const int bid = blockIdx.x;
  const int b = bid >> 7;
  const int rem = bid & 127;
  const int mb = rem >> 3;
  const int nb = rem & 7;

  const unsigned* selb = sel + b * TOPK_;
  const float* xb = x + (size_t)b * S_ * D_;
  float* outb = out + (size_t)b * S_ * D_;

  const int tid = threadIdx.x;
  const int lane = tid & 63;
  const int wid = tid >> 6;
  const int wm = wid >> 1;
  const int wn = wid & 1;

  const float* asrc[4];
  const float* bsrc[4];
  int srow_[4], sc4_[4];
#pragma unroll
  for (int r = 0; r < 4; ++r) {
    int flat = r * 512 + tid;
    int row = flat >> 4;
    int c4 = flat & 15;
    srow_[r] = row;
    sc4_[r] = c4;
    asrc[r] = xb + (size_t)selb[mb * BM + row] * D_ + c4 * 4;
    bsrc[r] = w + (size_t)(nb * BN + row) * D_ + c4 * 4;
  }

  f32x4 acc[2][4];
#pragma unroll
  for (int i = 0; i < 2; ++i)
#pragma unroll
    for (int j = 0; j < 4; ++j) acc[i][j] = (f32x4)0.0f;

  float4 pa[4], pb[4];
#pragma unroll
  for (int r = 0; r < 4; ++r) {
    pa[r] = *(const float4*)(asrc[r]);
    pb[r] = *(const float4*)(bsrc[r]);
  }

  for (int t = 0; t < NT; ++t) {
#pragma unroll
    for (int r = 0; r < 4; ++r) {
      int row = srow_[r], c4 = sc4_[r];
      int byte = row * 128 + c4 * 8;
      byte ^= (row & 7) << 4;
      uint2 va = make_uint2(pack2bf16(pa[r].x, pa[r].y), pack2bf16(pa[r].z, pa[r].w));
      uint2 vb = make_uint2(pack2bf16(pb[r].x, pb[r].y), pack2bf16(pb[r].z, pb[r].w));
      *(uint2*)((char*)Alds + byte) = va;
      *(uint2*)((char*)Blds + byte) = vb;
    }
    __syncthreads();

    if (t + 1 < NT) {
      const int koff = (t + 1) * BK;
#pragma unroll
      for (int r = 0; r < 4; ++r) {
        pa[r] = *(const float4*)(asrc[r] + koff);
        pb[r] = *(const float4*)(bsrc[r] + koff);
      }
    }

#pragma unroll
    for (int kk = 0; kk < 2; ++kk) {
      bf16x8 af[2], bfr[4];
#pragma unroll
      for (int mi = 0; mi < 2; ++mi) {
        int rrow = wm * 32 + mi * 16 + (lane & 15);
        int byte = rrow * 128 + (kk * 32 + (lane >> 4) * 8) * 2;
        byte ^= (rrow & 7) << 4;
        af[mi] = *(const bf16x8*)((const char*)Alds + byte);
      }
#pragma unroll
      for (int nj = 0; nj < 4; ++nj) {
        int rrow = wn * 64 + nj * 16 + (lane & 15);
        int byte = rrow * 128 + (kk * 32 + (lane >> 4) * 8) * 2;
        byte ^= (rrow & 7) << 4;
        bfr[nj] = *(const bf16x8*)((const char*)Blds + byte);
      }
#pragma unroll
      for (int mi = 0; mi < 2; ++mi)
#pragma unroll
        for (int nj = 0; nj < 4; ++nj)
          acc[mi][nj] = __builtin_amdgcn_mfma_f32_16x16x32_bf16(af[mi], bfr[nj], acc[mi][nj], 0, 0, 0);
    }
    __syncthreads();
  }

#pragma unroll
  for (int mi = 0; mi < 2; ++mi) {
#pragma unroll
    for (int j = 0; j < 4; ++j) {
      int m = mb * BM + wm * 32 + mi * 16 + (lane >> 4) * 4 + j;
      unsigned srow = selb[m];
      float* orow = outb + (size_t)srow * D_;
#pragma unroll
      for (int nj = 0; nj < 4; ++nj) {
        int col = nb * BN + wn * 64 + nj * 16 + (lane & 15);
        orow[col] = acc[mi][nj][j];
      }
    }
  }
}

extern "C" void kernel_launch(void* const* d_in, const int* in_sizes, int n_in,
                              void* d_out, int out_size, void* d_ws, size_t ws_size,
                              hipStream_t stream) {
  (void)in_sizes; (void)n_in; (void)out_size; (void)ws_size;
  const float* x = (const float*)d_in[0];
  const float* wb = (const float*)d_in[1];
  const float* wr = (const float*)d_in[2];
  float* out = (float*)d_out;

  float* logits = (float*)d_ws;                                   // 64 KB
  unsigned* sel = (unsigned*)((char*)d_ws + (size_t)B_ * S_ * 4); // 32 KB
  unsigned* notsel = sel + (size_t)B_ * TOPK_;                    // 32 KB

  k_router<<<B_ * S_ / 4, 256, 0, stream>>>(x, wr, logits);
  k_select<<<B_, 1024, 0, stream>>>(logits, sel, notsel);
  k_copy_rows<<<B_ * NSEL_, 256, 0, stream>>>(x, notsel, out);
  k_gemm_scatter<<<B_ * (TOPK_ / BM) * (D_ / BN), 512, 0, stream>>>(x, wb, sel, out);
}

// Round 3
// 62.490 us; speedup vs baseline: 2.0446x; 1.2685x over previous
//
#include <hip/hip_runtime.h>
#include <hip/hip_bf16.h>
#include <stdint.h>

#define B_ 4
#define S_ 4096
#define D_ 1024
#define TOPK_ 2048
#define NSEL_ (S_ - TOPK_)

#define BM 128
#define BN 128
#define BK 64
#define NT (D_ / BK)  // 16

typedef __attribute__((ext_vector_type(8))) short bf16x8;
typedef __attribute__((ext_vector_type(4))) float f32x4;

// RNE fp32 -> bf16 pack (two floats -> one u32, low|high)
__device__ __forceinline__ unsigned pack2bf16(float a, float b) {
  unsigned ua = __float_as_uint(a);
  unsigned ub = __float_as_uint(b);
  ua += 0x7fffu + ((ua >> 16) & 1u);
  ub += 0x7fffu + ((ub >> 16) & 1u);
  return (ua >> 16) | (ub & 0xffff0000u);
}

__device__ __forceinline__ unsigned mono_u32(float f) {
  unsigned u = __float_as_uint(f);
  return (u & 0x80000000u) ? ~u : (u | 0x80000000u);
}

__device__ __forceinline__ void gload_lds16(const void* g, void* l) {
  __builtin_amdgcn_global_load_lds(
      (const __attribute__((address_space(1))) void*)g,
      (__attribute__((address_space(3))) void*)l, 16, 0, 0);
}

// ---------------- K1: router logits (+ optional x->bf16 copy) ----------------
__global__ __launch_bounds__(256) void k_router(
    const float* __restrict__ x, const float* __restrict__ wr,
    float* __restrict__ logits, unsigned short* __restrict__ xbf) {
  const int lane = threadIdx.x & 63;
  const int token = blockIdx.x * 4 + (threadIdx.x >> 6);
  const float4* xr = (const float4*)(x + (size_t)token * D_);
  const float4* wrow = (const float4*)wr;
  double acc = 0.0;
#pragma unroll
  for (int i = 0; i < 4; ++i) {
    float4 v = xr[i * 64 + lane];
    float4 w = wrow[i * 64 + lane];
    if (xbf) {
      uint2 p = make_uint2(pack2bf16(v.x, v.y), pack2bf16(v.z, v.w));
      *(uint2*)(xbf + (size_t)token * D_ + i * 256 + lane * 4) = p;
    }
    acc += (double)v.x * (double)w.x + (double)v.y * (double)w.y +
           (double)v.z * (double)w.z + (double)v.w * (double)w.w;
  }
#pragma unroll
  for (int off = 32; off; off >>= 1) acc += __shfl_down(acc, off);
  if (lane == 0) logits[token] = (float)acc;
}

// ---------------- K1b: W fp32 -> bf16 ----------------
__global__ __launch_bounds__(256) void k_wconv(
    const float* __restrict__ w, unsigned short* __restrict__ wbf) {
  const int i = blockIdx.x * 256 + threadIdx.x;
  float4 v = ((const float4*)w)[i];
  *(uint2*)(wbf + (size_t)i * 4) = make_uint2(pack2bf16(v.x, v.y), pack2bf16(v.z, v.w));
}

// ---------------- K2: exact top-k via 4-pass radix select ----------------
__global__ __launch_bounds__(1024) void k_select(
    const float* __restrict__ logits, unsigned* __restrict__ sel,
    unsigned* __restrict__ notsel) {
  __shared__ unsigned hist[256];
  __shared__ unsigned bc_digit, bc_need;
  __shared__ unsigned scanbuf[17];

  const int b = blockIdx.x;
  const int tid = threadIdx.x;
  const int lane = tid & 63;
  const int wave = tid >> 6;

  float4 v = *(const float4*)(logits + b * S_ + tid * 4);
  unsigned k0 = mono_u32(v.x), k1 = mono_u32(v.y),
           k2 = mono_u32(v.z), k3 = mono_u32(v.w);

  unsigned prefix = 0, need = TOPK_;
#pragma unroll
  for (int pass = 0; pass < 4; ++pass) {
    const int shift = 24 - pass * 8;
    const unsigned maskhi = pass ? (0xFFFFFFFFu << (shift + 8)) : 0u;
    if (tid < 256) hist[tid] = 0;
    __syncthreads();
    if ((k0 & maskhi) == prefix) atomicAdd(&hist[(k0 >> shift) & 255], 1u);
    if ((k1 & maskhi) == prefix) atomicAdd(&hist[(k1 >> shift) & 255], 1u);
    if ((k2 & maskhi) == prefix) atomicAdd(&hist[(k2 >> shift) & 255], 1u);
    if ((k3 & maskhi) == prefix) atomicAdd(&hist[(k3 >> shift) & 255], 1u);
    __syncthreads();
    if (wave == 0) {
      uint4 h = *(const uint4*)(hist + lane * 4);
      unsigned t = h.x + h.y + h.z + h.w;
      unsigned inc = t;
#pragma unroll
      for (int off = 1; off < 64; off <<= 1) {
        unsigned u = __shfl_up(inc, off);
        if (lane >= off) inc += u;
      }
      unsigned total = __shfl(inc, 63);
      unsigned above = total - inc;
      unsigned a3 = above;
      unsigned a2 = a3 + h.w;
      unsigned a1 = a2 + h.z;
      unsigned a0 = a1 + h.y;
      if (a3 < need && need <= a3 + h.w) { bc_digit = lane * 4 + 3; bc_need = need - a3; }
      else if (a2 < need && need <= a2 + h.z) { bc_digit = lane * 4 + 2; bc_need = need - a2; }
      else if (a1 < need && need <= a1 + h.y) { bc_digit = lane * 4 + 1; bc_need = need - a1; }
      else if (a0 < need && need <= a0 + h.x) { bc_digit = lane * 4 + 0; bc_need = need - a0; }
    }
    __syncthreads();
    prefix |= bc_digit << shift;
    need = bc_need;
  }

  const unsigned V = prefix;
  const unsigned fneed = need;

  unsigned packed = 0;
  unsigned pk_excl0, pk_excl1, pk_excl2, pk_excl3;
  pk_excl0 = packed; if (k0 > V) packed += 1u << 16; else if (k0 == V) packed += 1u;
  pk_excl1 = packed; if (k1 > V) packed += 1u << 16; else if (k1 == V) packed += 1u;
  pk_excl2 = packed; if (k2 > V) packed += 1u << 16; else if (k2 == V) packed += 1u;
  pk_excl3 = packed; if (k3 > V) packed += 1u << 16; else if (k3 == V) packed += 1u;

  unsigned inc = packed;
#pragma unroll
  for (int off = 1; off < 64; off <<= 1) {
    unsigned u = __shfl_up(inc, off);
    if (lane >= off) inc += u;
  }
  if (lane == 63) scanbuf[wave] = inc;
  __syncthreads();
  if (tid < 16) {
    unsigned t = scanbuf[tid];
    unsigned winc = t;
#pragma unroll
    for (int off = 1; off < 16; off <<= 1) {
      unsigned u = __shfl_up(winc, off);
      if (tid >= off) winc += u;
    }
    scanbuf[tid] = winc - t;
    if (tid == 15) scanbuf[16] = winc;
  }
  __syncthreads();
  const unsigned base = scanbuf[wave] + (inc - packed);
  const unsigned G_total = scanbuf[16] >> 16;

  unsigned* selb = sel + b * TOPK_;
  unsigned* notb = notsel + b * NSEL_;
#pragma unroll
  for (int i = 0; i < 4; ++i) {
    unsigned ki = (i == 0) ? k0 : (i == 1) ? k1 : (i == 2) ? k2 : k3;
    unsigned pe = (i == 0) ? pk_excl0 : (i == 1) ? pk_excl1 : (i == 2) ? pk_excl2 : pk_excl3;
    unsigned s = tid * 4 + i;
    unsigned gtE = (base + pe) >> 16;
    unsigned eqE = (base + pe) & 0xFFFFu;
    if (ki > V) {
      selb[gtE] = s;
    } else if (ki == V && eqE < fneed) {
      selb[G_total + eqE] = s;
    } else {
      unsigned eqTaken = (eqE < fneed) ? eqE : fneed;
      notb[s - gtE - eqTaken] = s;
    }
  }
}

// ---------------- K3: copy non-selected rows ----------------
__global__ __launch_bounds__(256) void k_copy_rows(
    const float* __restrict__ x, const unsigned* __restrict__ notsel,
    float* __restrict__ out) {
  const int r = blockIdx.x;
  const int b = r >> 11;
  const unsigned s = notsel[r];
  const size_t off = ((size_t)b * S_ + s) * D_;
  ((float4*)(out + off))[threadIdx.x] = ((const float4*)(x + off))[threadIdx.x];
}

// ---------------- K4 (fast): bf16 gathered GEMM, global_load_lds + dbuf ----------------
// C[m,e] = sum_d xbf[b, sel[m], d] * wbf[e, d]
// LDS layout swizzled: physical 16B chunk (row, c) holds logical col-chunk c^(row&7).
// Staging: linear LDS dest, inverse-swizzled per-lane global source (rule #21).
__global__ __launch_bounds__(512) void k_gemm_lds(
    const unsigned short* __restrict__ xbf, const unsigned short* __restrict__ wbf,
    const unsigned* __restrict__ sel, float* __restrict__ out) {
  __shared__ __align__(16) unsigned short Alds[2][BM * BK];
  __shared__ __align__(16) unsigned short Blds[2][BN * BK];

  // XCD-aware swizzle: 512 blocks, XCD = bid%8 -> give each XCD 8 contiguous
  // M-panels x all 8 N-tiles (working set ~2MB A + 2MB W ~= L2).
  const int bid = blockIdx.x;
  const int gtile = (bid & 7) * 64 + (bid >> 3);
  const int mtile = gtile >> 3;  // 0..63
  const int nb = gtile & 7;
  const int b = mtile >> 4;
  const int mb = mtile & 15;

  const unsigned* selb = sel + b * TOPK_;
  const unsigned short* xb = xbf + (size_t)b * S_ * D_;
  float* outb = out + (size_t)b * S_ * D_;

  const int tid = threadIdx.x;
  const int lane = tid & 63;
  const int wid = tid >> 6;
  const int wm = wid >> 1;
  const int wn = wid & 1;

  // staging: 1024 chunks of 16B per tile; thread covers chunks {tid, tid+512}
  const unsigned short* asrc[2];
  const unsigned short* bsrc[2];
  unsigned ldsoff[2];
#pragma unroll
  for (int r = 0; r < 2; ++r) {
    int chunk = r * 512 + tid;
    int row = chunk >> 3, c16 = chunk & 7;
    int sw = c16 ^ (row & 7);  // inverse swizzle on source
    asrc[r] = xb + (size_t)selb[mb * BM + row] * D_ + sw * 8;
    bsrc[r] = wbf + (size_t)(nb * BN + row) * D_ + sw * 8;
    ldsoff[r] = chunk * 16;  // linear LDS dest
  }

  // compute-side swizzled ds_read byte offsets
  unsigned aoff[2][2], boff[4][2];
#pragma unroll
  for (int mi = 0; mi < 2; ++mi)
#pragma unroll
    for (int kk = 0; kk < 2; ++kk) {
      int rrow = wm * 32 + mi * 16 + (lane & 15);
      int byte = rrow * 128 + kk * 64 + (lane >> 4) * 16;
      aoff[mi][kk] = byte ^ ((rrow & 7) << 4);
    }
#pragma unroll
  for (int nj = 0; nj < 4; ++nj)
#pragma unroll
    for (int kk = 0; kk < 2; ++kk) {
      int rrow = wn * 64 + nj * 16 + (lane & 15);
      int byte = rrow * 128 + kk * 64 + (lane >> 4) * 16;
      boff[nj][kk] = byte ^ ((rrow & 7) << 4);
    }

  f32x4 acc[2][4];
#pragma unroll
  for (int i = 0; i < 2; ++i)
#pragma unroll
    for (int j = 0; j < 4; ++j) acc[i][j] = (f32x4)0.0f;

  // prologue stage tile 0 into buf 0
#pragma unroll
  for (int r = 0; r < 2; ++r) {
    gload_lds16(asrc[r], (char*)&Alds[0][0] + ldsoff[r]);
    gload_lds16(bsrc[r], (char*)&Blds[0][0] + ldsoff[r]);
  }
  __syncthreads();

  int cur = 0;
  for (int t = 0; t < NT; ++t) {
    if (t + 1 < NT) {
      const int koff = (t + 1) * BK;
#pragma unroll
      for (int r = 0; r < 2; ++r) {
        gload_lds16(asrc[r] + koff, (char*)&Alds[cur ^ 1][0] + ldsoff[r]);
        gload_lds16(bsrc[r] + koff, (char*)&Blds[cur ^ 1][0] + ldsoff[r]);
      }
    }
#pragma unroll
    for (int kk = 0; kk < 2; ++kk) {
      bf16x8 af[2], bfr[4];
#pragma unroll
      for (int mi = 0; mi < 2; ++mi)
        af[mi] = *(const bf16x8*)((const char*)&Alds[cur][0] + aoff[mi][kk]);
#pragma unroll
      for (int nj = 0; nj < 4; ++nj)
        bfr[nj] = *(const bf16x8*)((const char*)&Blds[cur][0] + boff[nj][kk]);
#pragma unroll
      for (int mi = 0; mi < 2; ++mi)
#pragma unroll
        for (int nj = 0; nj < 4; ++nj)
          acc[mi][nj] = __builtin_amdgcn_mfma_f32_16x16x32_bf16(af[mi], bfr[nj], acc[mi][nj], 0, 0, 0);
    }
    __syncthreads();  // drains vmcnt (staged loads) + lgkm; protects dbuf swap
    cur ^= 1;
  }

#pragma unroll
  for (int mi = 0; mi < 2; ++mi) {
#pragma unroll
    for (int j = 0; j < 4; ++j) {
      int m = mb * BM + wm * 32 + mi * 16 + (lane >> 4) * 4 + j;
      unsigned srow = selb[m];
      float* orow = outb + (size_t)srow * D_;
#pragma unroll
      for (int nj = 0; nj < 4; ++nj) {
        int col = nb * BN + wn * 64 + nj * 16 + (lane & 15);
        orow[col] = acc[mi][nj][j];
      }
    }
  }
}

// ---------------- K4 (fallback): round-2 reg-staged GEMM ----------------
__global__ __launch_bounds__(512) void k_gemm_reg(
    const float* __restrict__ x, const float* __restrict__ w,
    const unsigned* __restrict__ sel, float* __restrict__ out) {
  __shared__ __align__(16) unsigned short Alds[BM * BK];
  __shared__ __align__(16) unsigned short Blds[BN * BK];

  const int bid = blockIdx.x;
  const int b = bid >> 7;
  const int rem = bid & 127;
  const int mb = rem >> 3;
  const int nb = rem & 7;

  const unsigned* selb = sel + b * TOPK_;
  const float* xb = x + (size_t)b * S_ * D_;
  float* outb = out + (size_t)b * S_ * D_;

  const int tid = threadIdx.x;
  const int lane = tid & 63;
  const int wid = tid >> 6;
  const int wm = wid >> 1;
  const int wn = wid & 1;

  const float* asrc[4];
  const float* bsrc[4];
  int srow_[4], sc4_[4];
#pragma unroll
  for (int r = 0; r < 4; ++r) {
    int flat = r * 512 + tid;
    int row = flat >> 4;
    int c4 = flat & 15;
    srow_[r] = row;
    sc4_[r] = c4;
    asrc[r] = xb + (size_t)selb[mb * BM + row] * D_ + c4 * 4;
    bsrc[r] = w + (size_t)(nb * BN + row) * D_ + c4 * 4;
  }

  f32x4 acc[2][4];
#pragma unroll
  for (int i = 0; i < 2; ++i)
#pragma unroll
    for (int j = 0; j < 4; ++j) acc[i][j] = (f32x4)0.0f;

  float4 pa[4], pb[4];
#pragma unroll
  for (int r = 0; r < 4; ++r) {
    pa[r] = *(const float4*)(asrc[r]);
    pb[r] = *(const float4*)(bsrc[r]);
  }

  for (int t = 0; t < NT; ++t) {
#pragma unroll
    for (int r = 0; r < 4; ++r) {
      int row = srow_[r], c4 = sc4_[r];
      int byte = row * 128 + c4 * 8;
      byte ^= (row & 7) << 4;
      uint2 va = make_uint2(pack2bf16(pa[r].x, pa[r].y), pack2bf16(pa[r].z, pa[r].w));
      uint2 vb = make_uint2(pack2bf16(pb[r].x, pb[r].y), pack2bf16(pb[r].z, pb[r].w));
      *(uint2*)((char*)Alds + byte) = va;
      *(uint2*)((char*)Blds + byte) = vb;
    }
    __syncthreads();

    if (t + 1 < NT) {
      const int koff = (t + 1) * BK;
#pragma unroll
      for (int r = 0; r < 4; ++r) {
        pa[r] = *(const float4*)(asrc[r] + koff);
        pb[r] = *(const float4*)(bsrc[r] + koff);
      }
    }

#pragma unroll
    for (int kk = 0; kk < 2; ++kk) {
      bf16x8 af[2], bfr[4];
#pragma unroll
      for (int mi = 0; mi < 2; ++mi) {
        int rrow = wm * 32 + mi * 16 + (lane & 15);
        int byte = rrow * 128 + (kk * 32 + (lane >> 4) * 8) * 2;
        byte ^= (rrow & 7) << 4;
        af[mi] = *(const bf16x8*)((const char*)Alds + byte);
      }
#pragma unroll
      for (int nj = 0; nj < 4; ++nj) {
        int rrow = wn * 64 + nj * 16 + (lane & 15);
        int byte = rrow * 128 + (kk * 32 + (lane >> 4) * 8) * 2;
        byte ^= (rrow & 7) << 4;
        bfr[nj] = *(const bf16x8*)((const char*)Blds + byte);
      }
#pragma unroll
      for (int mi = 0; mi < 2; ++mi)
#pragma unroll
        for (int nj = 0; nj < 4; ++nj)
          acc[mi][nj] = __builtin_amdgcn_mfma_f32_16x16x32_bf16(af[mi], bfr[nj], acc[mi][nj], 0, 0, 0);
    }
    __syncthreads();
  }

#pragma unroll
  for (int mi = 0; mi < 2; ++mi) {
#pragma unroll
    for (int j = 0; j < 4; ++j) {
      int m = mb * BM + wm * 32 + mi * 16 + (lane >> 4) * 4 + j;
      unsigned srow = selb[m];
      float* orow = outb + (size_t)srow * D_;
#pragma unroll
      for (int nj = 0; nj < 4; ++nj) {
        int col = nb * BN + wn * 64 + nj * 16 + (lane & 15);
        orow[col] = acc[mi][nj][j];
      }
    }
  }
}

extern "C" void kernel_launch(void* const* d_in, const int* in_sizes, int n_in,
                              void* d_out, int out_size, void* d_ws, size_t ws_size,
                              hipStream_t stream) {
  (void)in_sizes; (void)n_in; (void)out_size;
  const float* x = (const float*)d_in[0];
  const float* wb = (const float*)d_in[1];
  const float* wr = (const float*)d_in[2];
  float* out = (float*)d_out;

  char* ws = (char*)d_ws;
  float* logits = (float*)ws;                                  // 64 KB
  unsigned* sel = (unsigned*)(ws + 65536);                     // 32 KB
  unsigned* notsel = sel + (size_t)B_ * TOPK_;                 // 32 KB -> ends at 128 KB
  unsigned short* xbf = (unsigned short*)(ws + 131072);        // 33.55 MB
  unsigned short* wbf = (unsigned short*)(ws + 131072 + (size_t)B_ * S_ * D_ * 2);  // 2 MB
  const size_t NEED = 131072 + (size_t)B_ * S_ * D_ * 2 + (size_t)D_ * D_ * 2;
  const bool fast = ws_size >= NEED;

  k_router<<<B_ * S_ / 4, 256, 0, stream>>>(x, wr, logits, fast ? xbf : nullptr);
  if (fast) k_wconv<<<D_ * D_ / 4 / 256, 256, 0, stream>>>(wb, wbf);
  k_select<<<B_, 1024, 0, stream>>>(logits, sel, notsel);
  k_copy_rows<<<B_ * NSEL_, 256, 0, stream>>>(x, notsel, out);
  if (fast)
    k_gemm_lds<<<B_ * (TOPK_ / BM) * (D_ / BN), 512, 0, stream>>>(xbf, wbf, sel, out);
  else
    k_gemm_reg<<<B_ * (TOPK_ / BM) * (D_ / BN), 512, 0, stream>>>(x, wb, sel, out);
}

// Round 4
// 58.374 us; speedup vs baseline: 2.1888x; 1.0705x over previous
//
#include <hip/hip_runtime.h>
#include <hip/hip_bf16.h>
#include <stdint.h>

#define B_ 4
#define S_ 4096
#define D_ 1024
#define TOPK_ 2048
#define NSEL_ (S_ - TOPK_)

#define BM 128
#define BN 128
#define BK 64
#define NT (D_ / BK)       // 16
#define GEMM_BLOCKS (B_ * (TOPK_ / BM) * (D_ / BN))  // 512
#define COPY_BLOCKS (B_ * NSEL_ / 2)                 // 4096

typedef __attribute__((ext_vector_type(8))) short bf16x8;
typedef __attribute__((ext_vector_type(4))) float f32x4;

// RNE fp32 -> bf16 pack (two floats -> one u32, low|high)
__device__ __forceinline__ unsigned pack2bf16(float a, float b) {
  unsigned ua = __float_as_uint(a);
  unsigned ub = __float_as_uint(b);
  ua += 0x7fffu + ((ua >> 16) & 1u);
  ub += 0x7fffu + ((ub >> 16) & 1u);
  return (ua >> 16) | (ub & 0xffff0000u);
}

__device__ __forceinline__ unsigned mono_u32(float f) {
  unsigned u = __float_as_uint(f);
  return (u & 0x80000000u) ? ~u : (u | 0x80000000u);
}

__device__ __forceinline__ void gload_lds16(const void* g, void* l) {
  __builtin_amdgcn_global_load_lds(
      (const __attribute__((address_space(1))) void*)g,
      (__attribute__((address_space(3))) void*)l, 16, 0, 0);
}

// ---------------- K1: router logits + x->bf16, blocks >=4096 do W->bf16 ----------------
__global__ __launch_bounds__(256) void k_router_fused(
    const float* __restrict__ x, const float* __restrict__ wr,
    float* __restrict__ logits, unsigned short* __restrict__ xbf,
    const float* __restrict__ wblock, unsigned short* __restrict__ wbf) {
  const int bid = blockIdx.x;
  if (bid >= B_ * S_ / 4) {
    // W fp32 -> bf16: 1024 blocks x 256 thr x 4 floats = D*D
    const int i = (bid - B_ * S_ / 4) * 256 + threadIdx.x;
    float4 v = ((const float4*)wblock)[i];
    *(uint2*)(wbf + (size_t)i * 4) =
        make_uint2(pack2bf16(v.x, v.y), pack2bf16(v.z, v.w));
    return;
  }
  const int lane = threadIdx.x & 63;
  const int token = bid * 4 + (threadIdx.x >> 6);
  const float4* xr = (const float4*)(x + (size_t)token * D_);
  const float4* wrow = (const float4*)wr;
  double acc = 0.0;
#pragma unroll
  for (int i = 0; i < 4; ++i) {
    float4 v = xr[i * 64 + lane];
    float4 w = wrow[i * 64 + lane];
    uint2 p = make_uint2(pack2bf16(v.x, v.y), pack2bf16(v.z, v.w));
    *(uint2*)(xbf + (size_t)token * D_ + i * 256 + lane * 4) = p;
    acc += (double)v.x * (double)w.x + (double)v.y * (double)w.y +
           (double)v.z * (double)w.z + (double)v.w * (double)w.w;
  }
#pragma unroll
  for (int off = 32; off; off >>= 1) acc += __shfl_down(acc, off);
  if (lane == 0) logits[token] = (float)acc;
}

// fallback router (no bf16 staging)
__global__ __launch_bounds__(256) void k_router_plain(
    const float* __restrict__ x, const float* __restrict__ wr,
    float* __restrict__ logits) {
  const int lane = threadIdx.x & 63;
  const int token = blockIdx.x * 4 + (threadIdx.x >> 6);
  const float4* xr = (const float4*)(x + (size_t)token * D_);
  const float4* wrow = (const float4*)wr;
  double acc = 0.0;
#pragma unroll
  for (int i = 0; i < 4; ++i) {
    float4 v = xr[i * 64 + lane];
    float4 w = wrow[i * 64 + lane];
    acc += (double)v.x * (double)w.x + (double)v.y * (double)w.y +
           (double)v.z * (double)w.z + (double)v.w * (double)w.w;
  }
#pragma unroll
  for (int off = 32; off; off >>= 1) acc += __shfl_down(acc, off);
  if (lane == 0) logits[token] = (float)acc;
}

// ---------------- K2: exact top-k via 4-pass radix select ----------------
__global__ __launch_bounds__(1024) void k_select(
    const float* __restrict__ logits, unsigned* __restrict__ sel,
    unsigned* __restrict__ notsel) {
  __shared__ unsigned hist[256];
  __shared__ unsigned bc_digit, bc_need;
  __shared__ unsigned scanbuf[17];

  const int b = blockIdx.x;
  const int tid = threadIdx.x;
  const int lane = tid & 63;
  const int wave = tid >> 6;

  float4 v = *(const float4*)(logits + b * S_ + tid * 4);
  unsigned k0 = mono_u32(v.x), k1 = mono_u32(v.y),
           k2 = mono_u32(v.z), k3 = mono_u32(v.w);

  unsigned prefix = 0, need = TOPK_;
#pragma unroll
  for (int pass = 0; pass < 4; ++pass) {
    const int shift = 24 - pass * 8;
    const unsigned maskhi = pass ? (0xFFFFFFFFu << (shift + 8)) : 0u;
    if (tid < 256) hist[tid] = 0;
    __syncthreads();
    if ((k0 & maskhi) == prefix) atomicAdd(&hist[(k0 >> shift) & 255], 1u);
    if ((k1 & maskhi) == prefix) atomicAdd(&hist[(k1 >> shift) & 255], 1u);
    if ((k2 & maskhi) == prefix) atomicAdd(&hist[(k2 >> shift) & 255], 1u);
    if ((k3 & maskhi) == prefix) atomicAdd(&hist[(k3 >> shift) & 255], 1u);
    __syncthreads();
    if (wave == 0) {
      uint4 h = *(const uint4*)(hist + lane * 4);
      unsigned t = h.x + h.y + h.z + h.w;
      unsigned inc = t;
#pragma unroll
      for (int off = 1; off < 64; off <<= 1) {
        unsigned u = __shfl_up(inc, off);
        if (lane >= off) inc += u;
      }
      unsigned total = __shfl(inc, 63);
      unsigned above = total - inc;
      unsigned a3 = above;
      unsigned a2 = a3 + h.w;
      unsigned a1 = a2 + h.z;
      unsigned a0 = a1 + h.y;
      if (a3 < need && need <= a3 + h.w) { bc_digit = lane * 4 + 3; bc_need = need - a3; }
      else if (a2 < need && need <= a2 + h.z) { bc_digit = lane * 4 + 2; bc_need = need - a2; }
      else if (a1 < need && need <= a1 + h.y) { bc_digit = lane * 4 + 1; bc_need = need - a1; }
      else if (a0 < need && need <= a0 + h.x) { bc_digit = lane * 4 + 0; bc_need = need - a0; }
    }
    __syncthreads();
    prefix |= bc_digit << shift;
    need = bc_need;
  }

  const unsigned V = prefix;
  const unsigned fneed = need;

  unsigned packed = 0;
  unsigned pk_excl0, pk_excl1, pk_excl2, pk_excl3;
  pk_excl0 = packed; if (k0 > V) packed += 1u << 16; else if (k0 == V) packed += 1u;
  pk_excl1 = packed; if (k1 > V) packed += 1u << 16; else if (k1 == V) packed += 1u;
  pk_excl2 = packed; if (k2 > V) packed += 1u << 16; else if (k2 == V) packed += 1u;
  pk_excl3 = packed; if (k3 > V) packed += 1u << 16; else if (k3 == V) packed += 1u;

  unsigned inc = packed;
#pragma unroll
  for (int off = 1; off < 64; off <<= 1) {
    unsigned u = __shfl_up(inc, off);
    if (lane >= off) inc += u;
  }
  if (lane == 63) scanbuf[wave] = inc;
  __syncthreads();
  if (tid < 16) {
    unsigned t = scanbuf[tid];
    unsigned winc = t;
#pragma unroll
    for (int off = 1; off < 16; off <<= 1) {
      unsigned u = __shfl_up(winc, off);
      if (tid >= off) winc += u;
    }
    scanbuf[tid] = winc - t;
    if (tid == 15) scanbuf[16] = winc;
  }
  __syncthreads();
  const unsigned base = scanbuf[wave] + (inc - packed);
  const unsigned G_total = scanbuf[16] >> 16;

  unsigned* selb = sel + b * TOPK_;
  unsigned* notb = notsel + b * NSEL_;
#pragma unroll
  for (int i = 0; i < 4; ++i) {
    unsigned ki = (i == 0) ? k0 : (i == 1) ? k1 : (i == 2) ? k2 : k3;
    unsigned pe = (i == 0) ? pk_excl0 : (i == 1) ? pk_excl1 : (i == 2) ? pk_excl2 : pk_excl3;
    unsigned s = tid * 4 + i;
    unsigned gtE = (base + pe) >> 16;
    unsigned eqE = (base + pe) & 0xFFFFu;
    if (ki > V) {
      selb[gtE] = s;
    } else if (ki == V && eqE < fneed) {
      selb[G_total + eqE] = s;
    } else {
      unsigned eqTaken = (eqE < fneed) ? eqE : fneed;
      notb[s - gtE - eqTaken] = s;
    }
  }
}

// ---------------- K3 (fast): fused GEMM + complement-row copy ----------------
// blocks [0, GEMM_BLOCKS): bf16 gathered GEMM + scatter (m97-class, dbuf,
//   global_load_lds, XOR-swizzled LDS with inverse-swizzled source).
// blocks [GEMM_BLOCKS, +COPY_BLOCKS): copy 2 non-selected rows each (fp32,
//   reads are L3-resident after the router streamed x).
__global__ __launch_bounds__(512) void k_gemm_copy(
    const unsigned short* __restrict__ xbf, const unsigned short* __restrict__ wbf,
    const unsigned* __restrict__ sel, const unsigned* __restrict__ notsel,
    const float* __restrict__ x, float* __restrict__ out) {
  __shared__ __align__(16) unsigned short Alds[2][BM * BK];
  __shared__ __align__(16) unsigned short Blds[2][BN * BK];

  const int bid = blockIdx.x;
  const int tid = threadIdx.x;

  if (bid >= GEMM_BLOCKS) {
    // ---- copy path: row r = 2*(bid-GEMM_BLOCKS) + (tid>>8), col16 = tid&255
    const int r = (bid - GEMM_BLOCKS) * 2 + (tid >> 8);  // 0..B_*NSEL_-1
    const int b = r >> 11;                                // NSEL_ == 2048
    const unsigned s = notsel[r];                         // flat index == r layout
    const size_t off = ((size_t)b * S_ + s) * D_;
    ((float4*)(out + off))[tid & 255] = ((const float4*)(x + off))[tid & 255];
    return;
  }

  // ---- GEMM path
  // XCD-aware swizzle: XCD = bid&7 owns 8 contiguous M-panels x all 8 N-tiles.
  const int gtile = (bid & 7) * 64 + (bid >> 3);
  const int mtile = gtile >> 3;
  const int nb = gtile & 7;
  const int b = mtile >> 4;
  const int mb = mtile & 15;

  const unsigned* selb = sel + b * TOPK_;
  const unsigned short* xb = xbf + (size_t)b * S_ * D_;
  float* outb = out + (size_t)b * S_ * D_;

  const int lane = tid & 63;
  const int wid = tid >> 6;
  const int wm = wid >> 1;
  const int wn = wid & 1;

  const unsigned short* asrc[2];
  const unsigned short* bsrc[2];
  unsigned ldsoff[2];
#pragma unroll
  for (int r = 0; r < 2; ++r) {
    int chunk = r * 512 + tid;
    int row = chunk >> 3, c16 = chunk & 7;
    int sw = c16 ^ (row & 7);  // inverse swizzle on source, linear LDS dest
    asrc[r] = xb + (size_t)selb[mb * BM + row] * D_ + sw * 8;
    bsrc[r] = wbf + (size_t)(nb * BN + row) * D_ + sw * 8;
    ldsoff[r] = chunk * 16;
  }

  unsigned aoff[2][2], boff[4][2];
#pragma unroll
  for (int mi = 0; mi < 2; ++mi)
#pragma unroll
    for (int kk = 0; kk < 2; ++kk) {
      int rrow = wm * 32 + mi * 16 + (lane & 15);
      int byte = rrow * 128 + kk * 64 + (lane >> 4) * 16;
      aoff[mi][kk] = byte ^ ((rrow & 7) << 4);
    }
#pragma unroll
  for (int nj = 0; nj < 4; ++nj)
#pragma unroll
    for (int kk = 0; kk < 2; ++kk) {
      int rrow = wn * 64 + nj * 16 + (lane & 15);
      int byte = rrow * 128 + kk * 64 + (lane >> 4) * 16;
      boff[nj][kk] = byte ^ ((rrow & 7) << 4);
    }

  f32x4 acc[2][4];
#pragma unroll
  for (int i = 0; i < 2; ++i)
#pragma unroll
    for (int j = 0; j < 4; ++j) acc[i][j] = (f32x4)0.0f;

#pragma unroll
  for (int r = 0; r < 2; ++r) {
    gload_lds16(asrc[r], (char*)&Alds[0][0] + ldsoff[r]);
    gload_lds16(bsrc[r], (char*)&Blds[0][0] + ldsoff[r]);
  }
  __syncthreads();

  int cur = 0;
  for (int t = 0; t < NT; ++t) {
    if (t + 1 < NT) {
      const int koff = (t + 1) * BK;
#pragma unroll
      for (int r = 0; r < 2; ++r) {
        gload_lds16(asrc[r] + koff, (char*)&Alds[cur ^ 1][0] + ldsoff[r]);
        gload_lds16(bsrc[r] + koff, (char*)&Blds[cur ^ 1][0] + ldsoff[r]);
      }
    }
#pragma unroll
    for (int kk = 0; kk < 2; ++kk) {
      bf16x8 af[2], bfr[4];
#pragma unroll
      for (int mi = 0; mi < 2; ++mi)
        af[mi] = *(const bf16x8*)((const char*)&Alds[cur][0] + aoff[mi][kk]);
#pragma unroll
      for (int nj = 0; nj < 4; ++nj)
        bfr[nj] = *(const bf16x8*)((const char*)&Blds[cur][0] + boff[nj][kk]);
#pragma unroll
      for (int mi = 0; mi < 2; ++mi)
#pragma unroll
        for (int nj = 0; nj < 4; ++nj)
          acc[mi][nj] = __builtin_amdgcn_mfma_f32_16x16x32_bf16(af[mi], bfr[nj], acc[mi][nj], 0, 0, 0);
    }
    __syncthreads();
    cur ^= 1;
  }

#pragma unroll
  for (int mi = 0; mi < 2; ++mi) {
#pragma unroll
    for (int j = 0; j < 4; ++j) {
      int m = mb * BM + wm * 32 + mi * 16 + (lane >> 4) * 4 + j;
      unsigned srow = selb[m];
      float* orow = outb + (size_t)srow * D_;
#pragma unroll
      for (int nj = 0; nj < 4; ++nj) {
        int col = nb * BN + wn * 64 + nj * 16 + (lane & 15);
        orow[col] = acc[mi][nj][j];
      }
    }
  }
}

// ---------------- fallback: reg-staged GEMM + separate copy ----------------
__global__ __launch_bounds__(256) void k_copy_rows(
    const float* __restrict__ x, const unsigned* __restrict__ notsel,
    float* __restrict__ out) {
  const int r = blockIdx.x;
  const int b = r >> 11;
  const unsigned s = notsel[r];
  const size_t off = ((size_t)b * S_ + s) * D_;
  ((float4*)(out + off))[threadIdx.x] = ((const float4*)(x + off))[threadIdx.x];
}

__global__ __launch_bounds__(512) void k_gemm_reg(
    const float* __restrict__ x, const float* __restrict__ w,
    const unsigned* __restrict__ sel, float* __restrict__ out) {
  __shared__ __align__(16) unsigned short Alds[BM * BK];
  __shared__ __align__(16) unsigned short Blds[BN * BK];

  const int bid = blockIdx.x;
  const int b = bid >> 7;
  const int rem = bid & 127;
  const int mb = rem >> 3;
  const int nb = rem & 7;

  const unsigned* selb = sel + b * TOPK_;
  const float* xb = x + (size_t)b * S_ * D_;
  float* outb = out + (size_t)b * S_ * D_;

  const int tid = threadIdx.x;
  const int lane = tid & 63;
  const int wid = tid >> 6;
  const int wm = wid >> 1;
  const int wn = wid & 1;

  const float* asrc[4];
  const float* bsrc[4];
  int srow_[4], sc4_[4];
#pragma unroll
  for (int r = 0; r < 4; ++r) {
    int flat = r * 512 + tid;
    int row = flat >> 4;
    int c4 = flat & 15;
    srow_[r] = row;
    sc4_[r] = c4;
    asrc[r] = xb + (size_t)selb[mb * BM + row] * D_ + c4 * 4;
    bsrc[r] = w + (size_t)(nb * BN + row) * D_ + c4 * 4;
  }

  f32x4 acc[2][4];
#pragma unroll
  for (int i = 0; i < 2; ++i)
#pragma unroll
    for (int j = 0; j < 4; ++j) acc[i][j] = (f32x4)0.0f;

  float4 pa[4], pb[4];
#pragma unroll
  for (int r = 0; r < 4; ++r) {
    pa[r] = *(const float4*)(asrc[r]);
    pb[r] = *(const float4*)(bsrc[r]);
  }

  for (int t = 0; t < NT; ++t) {
#pragma unroll
    for (int r = 0; r < 4; ++r) {
      int row = srow_[r], c4 = sc4_[r];
      int byte = row * 128 + c4 * 8;
      byte ^= (row & 7) << 4;
      *(uint2*)((char*)Alds + byte) = make_uint2(pack2bf16(pa[r].x, pa[r].y), pack2bf16(pa[r].z, pa[r].w));
      *(uint2*)((char*)Blds + byte) = make_uint2(pack2bf16(pb[r].x, pb[r].y), pack2bf16(pb[r].z, pb[r].w));
    }
    __syncthreads();

    if (t + 1 < NT) {
      const int koff = (t + 1) * BK;
#pragma unroll
      for (int r = 0; r < 4; ++r) {
        pa[r] = *(const float4*)(asrc[r] + koff);
        pb[r] = *(const float4*)(bsrc[r] + koff);
      }
    }

#pragma unroll
    for (int kk = 0; kk < 2; ++kk) {
      bf16x8 af[2], bfr[4];
#pragma unroll
      for (int mi = 0; mi < 2; ++mi) {
        int rrow = wm * 32 + mi * 16 + (lane & 15);
        int byte = rrow * 128 + (kk * 32 + (lane >> 4) * 8) * 2;
        byte ^= (rrow & 7) << 4;
        af[mi] = *(const bf16x8*)((const char*)Alds + byte);
      }
#pragma unroll
      for (int nj = 0; nj < 4; ++nj) {
        int rrow = wn * 64 + nj * 16 + (lane & 15);
        int byte = rrow * 128 + (kk * 32 + (lane >> 4) * 8) * 2;
        byte ^= (rrow & 7) << 4;
        bfr[nj] = *(const bf16x8*)((const char*)Blds + byte);
      }
#pragma unroll
      for (int mi = 0; mi < 2; ++mi)
#pragma unroll
        for (int nj = 0; nj < 4; ++nj)
          acc[mi][nj] = __builtin_amdgcn_mfma_f32_16x16x32_bf16(af[mi], bfr[nj], acc[mi][nj], 0, 0, 0);
    }
    __syncthreads();
  }

#pragma unroll
  for (int mi = 0; mi < 2; ++mi) {
#pragma unroll
    for (int j = 0; j < 4; ++j) {
      int m = mb * BM + wm * 32 + mi * 16 + (lane >> 4) * 4 + j;
      unsigned srow = selb[m];
      float* orow = outb + (size_t)srow * D_;
#pragma unroll
      for (int nj = 0; nj < 4; ++nj) {
        int col = nb * BN + wn * 64 + nj * 16 + (lane & 15);
        orow[col] = acc[mi][nj][j];
      }
    }
  }
}

extern "C" void kernel_launch(void* const* d_in, const int* in_sizes, int n_in,
                              void* d_out, int out_size, void* d_ws, size_t ws_size,
                              hipStream_t stream) {
  (void)in_sizes; (void)n_in; (void)out_size;
  const float* x = (const float*)d_in[0];
  const float* wb = (const float*)d_in[1];
  const float* wr = (const float*)d_in[2];
  float* out = (float*)d_out;

  char* ws = (char*)d_ws;
  float* logits = (float*)ws;                                  // 64 KB
  unsigned* sel = (unsigned*)(ws + 65536);                     // 32 KB
  unsigned* notsel = sel + (size_t)B_ * TOPK_;                 // 32 KB -> 128 KB
  unsigned short* xbf = (unsigned short*)(ws + 131072);        // 33.55 MB
  unsigned short* wbf = (unsigned short*)(ws + 131072 + (size_t)B_ * S_ * D_ * 2);  // 2 MB
  const size_t NEED = 131072 + (size_t)B_ * S_ * D_ * 2 + (size_t)D_ * D_ * 2;
  const bool fast = ws_size >= NEED;

  if (fast) {
    k_router_fused<<<B_ * S_ / 4 + D_ * D_ / 1024, 256, 0, stream>>>(x, wr, logits, xbf, wb, wbf);
    k_select<<<B_, 1024, 0, stream>>>(logits, sel, notsel);
    k_gemm_copy<<<GEMM_BLOCKS + COPY_BLOCKS, 512, 0, stream>>>(xbf, wbf, sel, notsel, x, out);
  } else {
    k_router_plain<<<B_ * S_ / 4, 256, 0, stream>>>(x, wr, logits);
    k_select<<<B_, 1024, 0, stream>>>(logits, sel, notsel);
    k_copy_rows<<<B_ * NSEL_, 256, 0, stream>>>(x, notsel, out);
    k_gemm_reg<<<GEMM_BLOCKS, 512, 0, stream>>>(x, wb, sel, out);
  }
}